// Round 6
// baseline (831.508 us; speedup 1.0000x reference)
//
#include <hip/hip_runtime.h>
#include <math.h>

#define NN 768
#define H 8
#define F 16
#define HF 128
#define EIN 64
#define EOUT 64
#define E_EDGES 24576
#define SLOPE 0.2f
#define EPS 1e-5f

__device__ __forceinline__ float leaky(float x){ return x >= 0.f ? x : SLOPE*x; }
__device__ __forceinline__ float elu1(float x){ return x > 0.f ? x : expm1f(x); }

// ---------------- K0a: node projection GEMM ----------------
// chunk 0,1: npj[:, c*64..] = x @ Wp^T rows   chunk 2,3: opre = x @ Wskip^T
// M=768 (32/block), N=64 per chunk, K=128. grid = 24*4
__global__ __launch_bounds__(256,3) void k_proj2(
    const float* __restrict__ x, const float* __restrict__ Wp, const float* __restrict__ Wskip,
    float* __restrict__ npj, float* __restrict__ opre){
  __shared__ float4 Bsh[64*32];   // 32KB
  __shared__ float4 Ash[32*32];   // 16KB
  int tid = threadIdx.x;
  int tile = blockIdx.x >> 2, chunk = blockIdx.x & 3;
  int i0 = tile*32;
  const float4* Wsrc = (const float4*)((chunk < 2 ? Wp : Wskip) + (size_t)(chunk & 1)*64*HF);
  const float4* X4 = (const float4*)(x + (size_t)i0*HF);
  #pragma unroll
  for(int t=0;t<8;t++){
    int fi = tid + t*256;             // 0..2047
    int n = fi >> 5, s = fi & 31;
    Bsh[n*32 + (s ^ ((n>>2)&15))] = Wsrc[fi];
  }
  #pragma unroll
  for(int t=0;t<4;t++){
    int fi = tid + t*256;             // 0..1023
    int e = fi >> 5, s = fi & 31;
    Ash[e*32 + (s ^ ((e>>1)&15))] = X4[fi];
  }
  __syncthreads();
  int og = tid & 15, eg = tid >> 4;   // 4 outputs, 2 nodes
  int o0 = og*4, eb = eg*2;
  float acc[2][4] = {};
  #pragma unroll
  for(int s=0;s<32;s++){
    float4 a0 = Ash[(eb+0)*32 + (s ^ (((eb+0)>>1)&15))];
    float4 a1 = Ash[(eb+1)*32 + (s ^ (((eb+1)>>1)&15))];
    #pragma unroll
    for(int oo=0;oo<4;oo++){
      float4 b = Bsh[(o0+oo)*32 + (s ^ (((o0+oo)>>2)&15))];
      acc[0][oo] += a0.x*b.x + a0.y*b.y + a0.z*b.z + a0.w*b.w;
      acc[1][oo] += a1.x*b.x + a1.y*b.y + a1.z*b.z + a1.w*b.w;
    }
  }
  float* dst = (chunk < 2) ? npj : opre;
  int col = (chunk & 1)*64 + o0;
  #pragma unroll
  for(int ee=0;ee<2;ee++){
    float4 v; v.x=acc[ee][0]; v.y=acc[ee][1]; v.z=acc[ee][2]; v.w=acc[ee][3];
    *(float4*)(dst + (size_t)(i0+eb+ee)*HF + col) = v;
  }
}

// ---------------- K0b: score reductions ----------------
__global__ void k_scores(const float* __restrict__ npj, const float* __restrict__ ssrc,
                         const float* __restrict__ stgt, float* __restrict__ ss, float* __restrict__ st){
  int i = blockIdx.x, c = threadIdx.x;   // 128 threads
  float p = npj[i*HF + c];
  float v1 = p*ssrc[c], v2 = p*stgt[c];
  #pragma unroll
  for(int o=1;o<16;o<<=1){ v1 += __shfl_xor(v1,o); v2 += __shfl_xor(v2,o); }
  if((c&15)==0){ ss[i*H + (c>>4)] = v1; st[i*H + (c>>4)] = v2; }
}

// ---------------- K_list ----------------
__global__ void k_list(const float* __restrict__ mask, int* __restrict__ lists, int* __restrict__ cnt){
  int w = threadIdx.x >> 6, lane = threadIdx.x & 63;
  int i = blockIdx.x*4 + w;
  int base = 0;
  const float* mrow = mask + (size_t)i*NN;
  int* lrow = lists + (size_t)i*NN;
  for(int t=0;t<12;t++){
    int j = t*64 + lane;
    bool un = (mrow[j] == 0.0f);
    unsigned long long b = __ballot(un);
    if(un) lrow[base + __popcll(b & ((1ull<<lane)-1ull))] = j;
    base += (int)__popcll(b);
  }
  if(base == 0){
    for(int t=0;t<12;t++) lrow[t*64+lane] = t*64+lane;
    base = NN;
  }
  if(lane==0) cnt[i] = base;
}

// ---------------- K1': sparse fused edge-projection -> compact logits ----------------
__global__ __launch_bounds__(256,4) void k_logits_sparse(
    const float* __restrict__ edges, const float* __restrict__ Wp2,
    const float* __restrict__ bp2, const float* __restrict__ sce,
    const float* __restrict__ ss, const float* __restrict__ st,
    const float* __restrict__ mask,
    const int* __restrict__ lists, const int* __restrict__ cnt,
    float* __restrict__ logitc){
  __shared__ float4 wsh[HF*16];
  __shared__ float4 esh[4][2][16];
  __shared__ float bsh[HF], scsh[HF];
  int i = blockIdx.x, tid = threadIdx.x;
  const float4* W4 = (const float4*)Wp2;
  #pragma unroll
  for(int t=0;t<8;t++) wsh[tid + t*256] = W4[tid + t*256];
  if(tid < HF){ bsh[tid]=bp2[tid]; scsh[tid]=sce[tid]; }
  __syncthreads();
  int w = tid>>6, lane = tid&63;
  int n = cnt[i];
  float ss0 = ss[i*H + (lane>>4)];
  float ss1 = ss[i*H + 4 + (lane>>4)];
  const int* lrow = lists + (size_t)i*NN;
  for(int s0 = w*2; s0 < n; s0 += 8){
    int s1 = s0 + 1;
    int j0 = lrow[s0];
    int j1 = lrow[(s1 < n) ? s1 : s0];
    if(lane < 32){
      int which = lane >> 4, k4 = lane & 15;
      int jj = which ? j1 : j0;
      esh[w][which][k4] = ((const float4*)(edges + ((size_t)i*NN + jj)*EIN))[k4];
    }
    asm volatile("s_waitcnt lgkmcnt(0) vmcnt(0)" ::: "memory");
    __builtin_amdgcn_sched_barrier(0);
    float a00=0.f,a01=0.f,a10=0.f,a11=0.f;
    #pragma unroll
    for(int t=0;t<16;t++){
      int q = t ^ (lane & 15);
      float4 e0 = esh[w][0][q];
      float4 e1 = esh[w][1][q];
      float4 w0 = wsh[lane*16 + q];
      float4 w1 = wsh[(lane+64)*16 + q];
      a00 += e0.x*w0.x + e0.y*w0.y + e0.z*w0.z + e0.w*w0.w;
      a01 += e1.x*w0.x + e1.y*w0.y + e1.z*w0.z + e1.w*w0.w;
      a10 += e0.x*w1.x + e0.y*w1.y + e0.z*w1.z + e0.w*w1.w;
      a11 += e1.x*w1.x + e1.y*w1.y + e1.z*w1.z + e1.w*w1.w;
    }
    float p;
    p = a00 + bsh[lane];    float v0  = leaky(p)*scsh[lane];
    p = a01 + bsh[lane];    float v0b = leaky(p)*scsh[lane];
    p = a10 + bsh[lane+64]; float v1  = leaky(p)*scsh[lane+64];
    p = a11 + bsh[lane+64]; float v1b = leaky(p)*scsh[lane+64];
    #pragma unroll
    for(int o=1;o<16;o<<=1){
      v0 += __shfl_xor(v0,o); v0b += __shfl_xor(v0b,o);
      v1 += __shfl_xor(v1,o); v1b += __shfl_xor(v1b,o);
    }
    if((lane & 15) == 0){
      int h = lane >> 4;
      float m0 = mask[(size_t)i*NN + j0];
      logitc[((size_t)i*H + h)*NN + s0]     = leaky(v0) + leaky(ss0 + st[j0*H + h]) + m0;
      logitc[((size_t)i*H + h + 4)*NN + s0] = leaky(v1) + leaky(ss1 + st[j0*H + h + 4]) + m0;
      if(s1 < n){
        float m1 = mask[(size_t)i*NN + j1];
        logitc[((size_t)i*H + h)*NN + s1]     = leaky(v0b) + leaky(ss0 + st[j1*H + h]) + m1;
        logitc[((size_t)i*H + h + 4)*NN + s1] = leaky(v1b) + leaky(ss1 + st[j1*H + h + 4]) + m1;
      }
    }
  }
}

// ---------------- K2': compact softmax ----------------
__global__ void k_softmax_c(float* __restrict__ logitc, const int* __restrict__ cnt){
  int i = blockIdx.x;
  int g = threadIdx.x >> 5, l = threadIdx.x & 31;
  int n = cnt[i];
  float* row = logitc + ((size_t)i*H + g)*NN;
  float m = -1e30f;
  for(int s=l; s<n; s+=32) m = fmaxf(m, row[s]);
  #pragma unroll
  for(int o=1;o<32;o<<=1) m = fmaxf(m, __shfl_xor(m, o, 32));
  float sum = 0.f;
  for(int s=l; s<n; s+=32){ float e = expf(row[s]-m); row[s]=e; sum+=e; }
  #pragma unroll
  for(int o=1;o<32;o<<=1) sum += __shfl_xor(sum, o, 32);
  float inv = 1.f/sum;
  for(int s=l; s<n; s+=32) row[s] *= inv;
}

// ---------------- K3': sparse einsum ----------------
__global__ void k_einsum_c(const float* __restrict__ attnc, const int* __restrict__ lists,
                           const int* __restrict__ cnt, const float* __restrict__ npj,
                           float* __restrict__ opre){
  int i = blockIdx.x, c = threadIdx.x;
  int h = c >> 4;
  int n = cnt[i];
  const int* lrow = lists + (size_t)i*NN;
  const float* arow = attnc + ((size_t)i*H + h)*NN;
  float acc = opre[i*HF + c];
  #pragma unroll 4
  for(int s=0; s<n; s++) acc += arow[s] * npj[lrow[s]*HF + c];
  opre[i*HF+c] = acc;
}

// ---------------- K4: node BN stats ----------------
__global__ void k_bn_node_stats(const float* __restrict__ outn_pre, float* __restrict__ stats){
  int c = threadIdx.x & 127, half = threadIdx.x >> 7;
  int r0 = blockIdx.x*16 + half*8;
  float s1=0.f, s2=0.f;
  #pragma unroll
  for(int r=0;r<8;r++){ float v = outn_pre[(r0+r)*HF + c]; s1+=v; s2+=v*v; }
  __shared__ float l1[256], l2[256];
  l1[threadIdx.x]=s1; l2[threadIdx.x]=s2;
  __syncthreads();
  if(threadIdx.x < 128){
    s1 = l1[threadIdx.x] + l1[threadIdx.x+128];
    s2 = l2[threadIdx.x] + l2[threadIdx.x+128];
    atomicAdd(&stats[c], s1); atomicAdd(&stats[HF + c], s2);
  }
}

// ---------------- K5: node BN apply ----------------
__global__ void k_bn_node_apply(const float* __restrict__ outn_pre, const float* __restrict__ stats,
                                const float* __restrict__ g, const float* __restrict__ b,
                                const float* __restrict__ nbias, float* __restrict__ outn){
  int idx = blockIdx.x*256 + threadIdx.x;
  int c = idx & 127;
  float m  = stats[c] * (1.f/NN);
  float var = stats[HF+c]*(1.f/NN) - m*m;
  float xv = outn_pre[idx];
  float y = g[c]*(xv - m)/sqrtf(var + EPS) + b[c] + nbias[c];
  outn[idx] = elu1(y);
}

// ---------------- K6a: m = leaky(sef@Wf1^T+bf1), oes = sef@Wes^T ----------------
// M=24576 (32/block), N=128 (Wf1 rows 0-63, Wes rows 64-127), K=64. grid 768
__global__ __launch_bounds__(256,3) void k_mlp_a(
    const float* __restrict__ sef, const float* __restrict__ Wf1, const float* __restrict__ bf1,
    const float* __restrict__ Wes, float* __restrict__ m_out, float* __restrict__ oes_out){
  __shared__ float4 Bsh[128*16];   // 32KB
  __shared__ float4 Ash[32*16];    // 8KB
  __shared__ float b1sh[64];
  int tid = threadIdx.x;
  int e0 = blockIdx.x * 32;
  const float4* W1_4 = (const float4*)Wf1;
  const float4* We_4 = (const float4*)Wes;
  #pragma unroll
  for(int t=0;t<8;t++){
    int fi = tid + t*256;            // 0..2047
    int n = fi >> 4, s = fi & 15;
    float4 v = (n < 64) ? W1_4[n*16+s] : We_4[(n-64)*16+s];
    Bsh[n*16 + (s ^ ((n>>3)&15))] = v;
  }
  if(tid < 64) b1sh[tid] = bf1[tid];
  const float4* A4 = (const float4*)(sef + (size_t)e0*EIN);
  #pragma unroll
  for(int t=0;t<2;t++){
    int fi = tid + t*256;            // 0..511
    int e = fi >> 4, s = fi & 15;
    Ash[e*16 + (s ^ ((e>>1)&15))] = A4[fi];
  }
  __syncthreads();
  int og = tid & 15, eg = tid >> 4;  // 8 outputs, 2 edges
  int n0 = og*8, eb = eg*2;
  float acc[2][8] = {};
  #pragma unroll
  for(int s=0;s<16;s++){
    float4 a0 = Ash[(eb+0)*16 + (s ^ (((eb+0)>>1)&15))];
    float4 a1 = Ash[(eb+1)*16 + (s ^ (((eb+1)>>1)&15))];
    #pragma unroll
    for(int oo=0;oo<8;oo++){
      float4 b = Bsh[(n0+oo)*16 + (s ^ (((n0+oo)>>3)&15))];
      acc[0][oo] += a0.x*b.x + a0.y*b.y + a0.z*b.z + a0.w*b.w;
      acc[1][oo] += a1.x*b.x + a1.y*b.y + a1.z*b.z + a1.w*b.w;
    }
  }
  #pragma unroll
  for(int ee=0;ee<2;ee++){
    int e = e0 + eb + ee;
    if(og < 8){
      #pragma unroll
      for(int oo=0;oo<8;oo++) m_out[(size_t)e*EOUT + n0 + oo] = leaky(acc[ee][oo] + b1sh[n0+oo]);
    } else {
      #pragma unroll
      for(int oo=0;oo<8;oo++) oes_out[(size_t)e*EOUT + (n0-64) + oo] = acc[ee][oo];
    }
  }
}

// ---------------- K6b: r = leaky(dd@Wf2^T), dd = (outn[si]-outn[sj])^2 ----------------
// M=24576 (32/block), N=64, K=128. grid 768
__global__ __launch_bounds__(256,3) void k_mlp_b(
    const int* __restrict__ eidx, const float* __restrict__ outn,
    const float* __restrict__ Wf2, float* __restrict__ r_out){
  __shared__ float4 Bsh[64*32];    // 32KB
  __shared__ float4 Ash[32*32];    // 16KB
  int tid = threadIdx.x;
  int e0 = blockIdx.x * 32;
  const float4* W2_4 = (const float4*)Wf2;
  #pragma unroll
  for(int t=0;t<8;t++){
    int fi = tid + t*256;            // 0..2047
    int n = fi >> 5, s = fi & 31;
    Bsh[n*32 + (s ^ ((n>>2)&15))] = W2_4[fi];
  }
  const float4* O4 = (const float4*)outn;
  #pragma unroll
  for(int t=0;t<4;t++){
    int fi = tid + t*256;            // 0..1023
    int e = fi >> 5, s = fi & 31;
    int ed = e0 + e;
    int si = eidx[ed*2], sj = eidx[ed*2+1];
    float4 vi = O4[(size_t)si*32 + s];
    float4 vj = O4[(size_t)sj*32 + s];
    float4 d; d.x=vi.x-vj.x; d.y=vi.y-vj.y; d.z=vi.z-vj.z; d.w=vi.w-vj.w;
    d.x*=d.x; d.y*=d.y; d.z*=d.z; d.w*=d.w;
    Ash[e*32 + (s ^ ((e>>1)&15))] = d;
  }
  __syncthreads();
  int og = tid & 15, eg = tid >> 4;  // 4 outputs, 2 edges
  int o0 = og*4, eb = eg*2;
  float acc[2][4] = {};
  #pragma unroll
  for(int s=0;s<32;s++){
    float4 a0 = Ash[(eb+0)*32 + (s ^ (((eb+0)>>1)&15))];
    float4 a1 = Ash[(eb+1)*32 + (s ^ (((eb+1)>>1)&15))];
    #pragma unroll
    for(int oo=0;oo<4;oo++){
      float4 b = Bsh[(o0+oo)*32 + (s ^ (((o0+oo)>>2)&15))];
      acc[0][oo] += a0.x*b.x + a0.y*b.y + a0.z*b.z + a0.w*b.w;
      acc[1][oo] += a1.x*b.x + a1.y*b.y + a1.z*b.z + a1.w*b.w;
    }
  }
  #pragma unroll
  for(int ee=0;ee<2;ee++){
    float4 v; v.x=leaky(acc[ee][0]); v.y=leaky(acc[ee][1]); v.z=leaky(acc[ee][2]); v.w=leaky(acc[ee][3]);
    *(float4*)(r_out + (size_t)(e0+eb+ee)*EOUT + o0) = v;
  }
}

// ---------------- K6c: oe = [m|r]@Wf3^T + oes ----------------
// M=24576 (32/block), N=64, K=128. grid 768
__global__ __launch_bounds__(256,2) void k_mlp_c(
    const float* __restrict__ m_in, const float* __restrict__ r_in,
    const float* __restrict__ oes_in, const float* __restrict__ Wf3,
    float* __restrict__ oe_pre){
  __shared__ float4 Bsh[64*32];    // 32KB
  __shared__ float4 Ash[32*32];    // 32KB (slots 0-15 = m, 16-31 = r)
  int tid = threadIdx.x;
  int e0 = blockIdx.x * 32;
  const float4* W3_4 = (const float4*)Wf3;
  #pragma unroll
  for(int t=0;t<8;t++){
    int fi = tid + t*256;
    int n = fi >> 5, s = fi & 31;
    Bsh[n*32 + (s ^ ((n>>2)&15))] = W3_4[fi];
  }
  const float4* M4 = (const float4*)(m_in + (size_t)e0*EOUT);
  const float4* R4 = (const float4*)(r_in + (size_t)e0*EOUT);
  #pragma unroll
  for(int t=0;t<2;t++){
    int fi = tid + t*256;            // 0..511
    int e = fi >> 4, s = fi & 15;
    int sw = s ^ ((e>>1)&15);
    Ash[e*32 + sw] = M4[fi];
    Ash[e*32 + 16 + sw] = R4[fi];
  }
  __syncthreads();
  int og = tid & 15, eg = tid >> 4;
  int o0 = og*4, eb = eg*2;
  float acc[2][4] = {};
  #pragma unroll
  for(int s=0;s<32;s++){
    int half = s & 16, sl = s & 15;
    float4 a0 = Ash[(eb+0)*32 + half + (sl ^ (((eb+0)>>1)&15))];
    float4 a1 = Ash[(eb+1)*32 + half + (sl ^ (((eb+1)>>1)&15))];
    #pragma unroll
    for(int oo=0;oo<4;oo++){
      float4 b = Bsh[(o0+oo)*32 + (s ^ (((o0+oo)>>2)&15))];
      acc[0][oo] += a0.x*b.x + a0.y*b.y + a0.z*b.z + a0.w*b.w;
      acc[1][oo] += a1.x*b.x + a1.y*b.y + a1.z*b.z + a1.w*b.w;
    }
  }
  #pragma unroll
  for(int ee=0;ee<2;ee++){
    int e = e0 + eb + ee;
    float4 os = ((const float4*)oes_in)[(size_t)e*16 + og];
    float4 v; v.x=acc[ee][0]+os.x; v.y=acc[ee][1]+os.y; v.z=acc[ee][2]+os.z; v.w=acc[ee][3]+os.w;
    *(float4*)(oe_pre + (size_t)e*EOUT + o0) = v;
  }
}

// ---------------- K6d: edge BN stats ----------------
__global__ void k_bn_edge_stats(const float* __restrict__ oe_pre, float* __restrict__ stats){
  int c = threadIdx.x & 63, rg = threadIdx.x >> 6;
  int r0 = blockIdx.x*256 + rg*64;
  float s1=0.f, s2=0.f;
  for(int r=0;r<64;r++){ float v = oe_pre[(size_t)(r0+r)*EOUT + c]; s1+=v; s2+=v*v; }
  __shared__ float l1[256], l2[256];
  l1[threadIdx.x]=s1; l2[threadIdx.x]=s2;
  __syncthreads();
  if(threadIdx.x < 64){
    float a1 = l1[threadIdx.x] + l1[threadIdx.x+64] + l1[threadIdx.x+128] + l1[threadIdx.x+192];
    float a2 = l2[threadIdx.x] + l2[threadIdx.x+64] + l2[threadIdx.x+128] + l2[threadIdx.x+192];
    atomicAdd(&stats[256 + threadIdx.x], a1);
    atomicAdd(&stats[320 + threadIdx.x], a2);
  }
}

// ---------------- K7: edge BN apply ----------------
__global__ void k_bn_edge_apply(const float* __restrict__ oe_pre, const float* __restrict__ stats,
                                const float* __restrict__ g, const float* __restrict__ b,
                                float* __restrict__ oe_out){
  int idx = blockIdx.x*256 + threadIdx.x;
  int o = idx & 63;
  float m = stats[256+o] * (1.f/E_EDGES);
  float var = stats[320+o]*(1.f/E_EDGES) - m*m;
  float xv = oe_pre[idx];
  float y = g[o]*(xv-m)/sqrtf(var+EPS) + b[o];
  oe_out[idx] = elu1(y);
}

// ---------------- K8: ie nonzero fill ----------------
__global__ __launch_bounds__(256) void k_ie_fill(
    const float* __restrict__ edges, const float* __restrict__ mask,
    const float* __restrict__ Wf4, const float* __restrict__ bf4,
    float* __restrict__ ie){
  __shared__ float w4[64*65];
  __shared__ float b4sh[64];
  __shared__ int list[NN];
  __shared__ int lcnt;
  int i = blockIdx.x, tid = threadIdx.x;
  if(tid==0) lcnt = 0;
  for(int idx=tid; idx<64*64; idx+=256){ int o=idx>>6,k=idx&63; w4[o*65+k]=Wf4[idx]; }
  if(tid<64) b4sh[tid]=bf4[tid];
  __syncthreads();
  for(int t=0;t<3;t++){
    int j = tid + t*256;
    if(mask[i*NN+j] == 0.0f){ int p = atomicAdd(&lcnt,1); list[p]=j; }
  }
  __syncthreads();
  int cnt = lcnt;
  float inv;
  if(cnt == 0){
    for(int t=0;t<3;t++) list[tid+t*256] = tid+t*256;
    cnt = NN; inv = 1.0f/NN;
    __syncthreads();
  } else inv = 1.0f/cnt;
  int o = tid & 63, jj4 = tid >> 6;
  for(int base=0; base<cnt; base+=4){
    int li = base + jj4;
    if(li < cnt){
      int j = list[li];
      const float* er = edges + ((size_t)i*NN + j)*EIN;
      float acc = b4sh[o];
      #pragma unroll 8
      for(int k=0;k<64;k++) acc += er[k]*w4[o*65+k];
      ie[((size_t)i*NN + j)*EIN + o] = acc * inv;
    }
  }
}

// ---------------- K9: scatter ----------------
__global__ void k_winner(const int* __restrict__ eidx, int* __restrict__ winner){
  int e = blockIdx.x*256 + threadIdx.x;
  if(e < E_EDGES){
    int si = eidx[e*2], sj = eidx[e*2+1];
    atomicMax(&winner[si*NN+sj], e);
  }
}
__global__ void k_scatter(const int* __restrict__ eidx, const int* __restrict__ winner,
                          const float* __restrict__ oe, float* __restrict__ ie){
  int idx = blockIdx.x*256 + threadIdx.x;
  int e = idx >> 6, o = idx & 63;
  int si = eidx[e*2], sj = eidx[e*2+1];
  if(winner[si*NN+sj] == e) ie[((size_t)si*NN+sj)*EIN + o] = oe[(size_t)e*64+o];
}

// ---------------- K10: indices -> float ----------------
__global__ void k_idxf(const int* __restrict__ eidx, float* __restrict__ outf){
  int idx = blockIdx.x*256 + threadIdx.x;
  if(idx < E_EDGES*2) outf[idx] = (float)eidx[idx];
}

extern "C" void kernel_launch(void* const* d_in, const int* in_sizes, int n_in,
                              void* d_out, int out_size, void* d_ws, size_t ws_size,
                              hipStream_t stream){
  (void)in_sizes; (void)n_in; (void)out_size; (void)d_ws; (void)ws_size;
  const float* x     = (const float*)d_in[0];
  const float* edges = (const float*)d_in[1];
  const float* mask  = (const float*)d_in[2];
  const float* sef   = (const float*)d_in[3];
  const int*   eidx  = (const int*)d_in[4];
  const float* Wp    = (const float*)d_in[5];
  const float* Wp2   = (const float*)d_in[6];
  const float* bp2   = (const float*)d_in[7];
  const float* ssrc  = (const float*)d_in[8];
  const float* stgt  = (const float*)d_in[9];
  const float* sce   = (const float*)d_in[10];
  const float* Wskip = (const float*)d_in[11];
  const float* nbias = (const float*)d_in[12];
  const float* bng   = (const float*)d_in[13];
  const float* bnb   = (const float*)d_in[14];
  const float* Wf1   = (const float*)d_in[15];
  const float* bf1   = (const float*)d_in[16];
  const float* Wf2   = (const float*)d_in[17];
  const float* Wf3   = (const float*)d_in[18];
  const float* Wf4   = (const float*)d_in[19];
  const float* bf4   = (const float*)d_in[20];
  const float* Wes   = (const float*)d_in[21];
  const float* beg   = (const float*)d_in[22];
  const float* beb   = (const float*)d_in[23];

  float* out      = (float*)d_out;
  float* out_outn = out;                    // 98304
  float* out_ie   = out + 98304;            // 37748736
  float* out_mask = out + 37847040;         // 589824
  float* out_oe   = out + 38436864;         // 1572864
  float* out_idx  = out + 40009728;         // 49152

  // scratch carved out of the (not yet written) ie region
  float* s_logitc = out_ie;                 // 4718592
  float* s_npj    = out_ie + 4718592;       // 98304
  float* s_ss     = s_npj + 98304;          // 6144
  float* s_st     = s_ss + 6144;            // 6144
  float* s_opre   = s_st + 6144;            // 98304
  float* s_oepre  = s_opre + 98304;         // 1572864
  float* s_stats  = s_oepre + 1572864;      // 512
  int*   s_lists  = (int*)(s_stats + 512);  // 2359296
  int*   s_cnt    = s_lists + 2359296;      // 768
  float* s_m      = (float*)(s_cnt + 768);  // 1572864
  float* s_oes    = s_m + 1572864;          // 1572864
  float* s_r      = s_oes + 1572864;        // 1572864
  int*   winner   = (int*)out_mask;         // scratch until mask copied at end

  hipMemsetAsync(s_stats, 0, 512*sizeof(float), stream);
  hipMemsetAsync(winner, 0xFF, (size_t)NN*NN*sizeof(int), stream);

  k_list<<<NN/4, 256, 0, stream>>>(mask, s_lists, s_cnt);
  k_proj2<<<96, 256, 0, stream>>>(x, Wp, Wskip, s_npj, s_opre);
  k_scores<<<NN, 128, 0, stream>>>(s_npj, ssrc, stgt, s_ss, s_st);
  k_logits_sparse<<<NN, 256, 0, stream>>>(edges, Wp2, bp2, sce, s_ss, s_st, mask, s_lists, s_cnt, s_logitc);
  k_softmax_c<<<NN, 256, 0, stream>>>(s_logitc, s_cnt);
  k_einsum_c<<<NN, 128, 0, stream>>>(s_logitc, s_lists, s_cnt, s_npj, s_opre);
  k_bn_node_stats<<<48, 256, 0, stream>>>(s_opre, s_stats);
  k_bn_node_apply<<<384, 256, 0, stream>>>(s_opre, s_stats, bng, bnb, nbias, out_outn);
  k_mlp_a<<<E_EDGES/32, 256, 0, stream>>>(sef, Wf1, bf1, Wes, s_m, s_oes);
  k_mlp_b<<<E_EDGES/32, 256, 0, stream>>>(eidx, out_outn, Wf2, s_r);
  k_mlp_c<<<E_EDGES/32, 256, 0, stream>>>(s_m, s_r, s_oes, Wf3, s_oepre);
  k_bn_edge_stats<<<E_EDGES/256, 256, 0, stream>>>(s_oepre, s_stats);
  k_bn_edge_apply<<<6144, 256, 0, stream>>>(s_oepre, s_stats, beg, beb, out_oe);
  // all ie-region scratch consumed; now build ie
  hipMemsetAsync(out_ie, 0, (size_t)NN*NN*EIN*sizeof(float), stream);
  k_ie_fill<<<NN, 256, 0, stream>>>(edges, mask, Wf4, bf4, out_ie);
  k_winner<<<96, 256, 0, stream>>>(eidx, winner);
  k_scatter<<<6144, 256, 0, stream>>>(eidx, winner, out_oe, out_ie);
  hipMemcpyAsync(out_mask, mask, (size_t)NN*NN*sizeof(float), hipMemcpyDeviceToDevice, stream);
  k_idxf<<<192, 256, 0, stream>>>(eidx, out_idx);
}

// Round 7
// 831.379 us; speedup vs baseline: 1.0002x; 1.0002x over previous
//
#include <hip/hip_runtime.h>
#include <math.h>

#define NN 768
#define H 8
#define F 16
#define HF 128
#define EIN 64
#define EOUT 64
#define E_EDGES 24576
#define SLOPE 0.2f
#define EPS 1e-5f

__device__ __forceinline__ float leaky(float x){ return x >= 0.f ? x : SLOPE*x; }
__device__ __forceinline__ float elu1(float x){ return x > 0.f ? x : expm1f(x); }

// ---------------- K0a: node projection GEMM ----------------
__global__ __launch_bounds__(256,3) void k_proj2(
    const float* __restrict__ x, const float* __restrict__ Wp, const float* __restrict__ Wskip,
    float* __restrict__ npj, float* __restrict__ opre){
  __shared__ float4 Bsh[64*32];   // 32KB
  __shared__ float4 Ash[32*32];   // 16KB
  int tid = threadIdx.x;
  int tile = blockIdx.x >> 2, chunk = blockIdx.x & 3;
  int i0 = tile*32;
  const float4* Wsrc = (const float4*)((chunk < 2 ? Wp : Wskip) + (size_t)(chunk & 1)*64*HF);
  const float4* X4 = (const float4*)(x + (size_t)i0*HF);
  #pragma unroll
  for(int t=0;t<8;t++){
    int fi = tid + t*256;             // 0..2047
    int n = fi >> 5, s = fi & 31;
    Bsh[n*32 + (s ^ ((n>>2)&15))] = Wsrc[fi];
  }
  #pragma unroll
  for(int t=0;t<4;t++){
    int fi = tid + t*256;             // 0..1023
    int e = fi >> 5, s = fi & 31;
    Ash[e*32 + (s ^ ((e>>1)&15))] = X4[fi];
  }
  __syncthreads();
  int og = tid & 15, eg = tid >> 4;   // 4 outputs, 2 nodes
  int o0 = og*4, eb = eg*2;
  float acc[2][4] = {};
  #pragma unroll
  for(int s=0;s<32;s++){
    float4 a0 = Ash[(eb+0)*32 + (s ^ (((eb+0)>>1)&15))];
    float4 a1 = Ash[(eb+1)*32 + (s ^ (((eb+1)>>1)&15))];
    #pragma unroll
    for(int oo=0;oo<4;oo++){
      float4 b = Bsh[(o0+oo)*32 + (s ^ (((o0+oo)>>2)&15))];
      acc[0][oo] += a0.x*b.x + a0.y*b.y + a0.z*b.z + a0.w*b.w;
      acc[1][oo] += a1.x*b.x + a1.y*b.y + a1.z*b.z + a1.w*b.w;
    }
  }
  float* dst = (chunk < 2) ? npj : opre;
  int col = (chunk & 1)*64 + o0;
  #pragma unroll
  for(int ee=0;ee<2;ee++){
    float4 v; v.x=acc[ee][0]; v.y=acc[ee][1]; v.z=acc[ee][2]; v.w=acc[ee][3];
    *(float4*)(dst + (size_t)(i0+eb+ee)*HF + col) = v;
  }
}

// ---------------- K0b: score reductions ----------------
__global__ void k_scores(const float* __restrict__ npj, const float* __restrict__ ssrc,
                         const float* __restrict__ stgt, float* __restrict__ ss, float* __restrict__ st){
  int i = blockIdx.x, c = threadIdx.x;   // 128 threads
  float p = npj[i*HF + c];
  float v1 = p*ssrc[c], v2 = p*stgt[c];
  #pragma unroll
  for(int o=1;o<16;o<<=1){ v1 += __shfl_xor(v1,o); v2 += __shfl_xor(v2,o); }
  if((c&15)==0){ ss[i*H + (c>>4)] = v1; st[i*H + (c>>4)] = v2; }
}

// ---------------- K_list ----------------
__global__ void k_list(const float* __restrict__ mask, int* __restrict__ lists, int* __restrict__ cnt){
  int w = threadIdx.x >> 6, lane = threadIdx.x & 63;
  int i = blockIdx.x*4 + w;
  int base = 0;
  const float* mrow = mask + (size_t)i*NN;
  int* lrow = lists + (size_t)i*NN;
  for(int t=0;t<12;t++){
    int j = t*64 + lane;
    bool un = (mrow[j] == 0.0f);
    unsigned long long b = __ballot(un);
    if(un) lrow[base + __popcll(b & ((1ull<<lane)-1ull))] = j;
    base += (int)__popcll(b);
  }
  if(base == 0){
    for(int t=0;t<12;t++) lrow[t*64+lane] = t*64+lane;
    base = NN;
  }
  if(lane==0) cnt[i] = base;
}

// ---------------- K1': sparse fused edge-projection -> compact logits ----------------
__global__ __launch_bounds__(256,4) void k_logits_sparse(
    const float* __restrict__ edges, const float* __restrict__ Wp2,
    const float* __restrict__ bp2, const float* __restrict__ sce,
    const float* __restrict__ ss, const float* __restrict__ st,
    const float* __restrict__ mask,
    const int* __restrict__ lists, const int* __restrict__ cnt,
    float* __restrict__ logitc){
  __shared__ float4 wsh[HF*16];
  __shared__ float4 esh[4][2][16];
  __shared__ float bsh[HF], scsh[HF];
  int i = blockIdx.x, tid = threadIdx.x;
  const float4* W4 = (const float4*)Wp2;
  #pragma unroll
  for(int t=0;t<8;t++) wsh[tid + t*256] = W4[tid + t*256];
  if(tid < HF){ bsh[tid]=bp2[tid]; scsh[tid]=sce[tid]; }
  __syncthreads();
  int w = tid>>6, lane = tid&63;
  int n = cnt[i];
  float ss0 = ss[i*H + (lane>>4)];
  float ss1 = ss[i*H + 4 + (lane>>4)];
  const int* lrow = lists + (size_t)i*NN;
  for(int s0 = w*2; s0 < n; s0 += 8){
    int s1 = s0 + 1;
    int j0 = lrow[s0];
    int j1 = lrow[(s1 < n) ? s1 : s0];
    if(lane < 32){
      int which = lane >> 4, k4 = lane & 15;
      int jj = which ? j1 : j0;
      esh[w][which][k4] = ((const float4*)(edges + ((size_t)i*NN + jj)*EIN))[k4];
    }
    asm volatile("s_waitcnt lgkmcnt(0) vmcnt(0)" ::: "memory");
    __builtin_amdgcn_sched_barrier(0);
    float a00=0.f,a01=0.f,a10=0.f,a11=0.f;
    #pragma unroll
    for(int t=0;t<16;t++){
      int q = t ^ (lane & 15);
      float4 e0 = esh[w][0][q];
      float4 e1 = esh[w][1][q];
      float4 w0 = wsh[lane*16 + q];
      float4 w1 = wsh[(lane+64)*16 + q];
      a00 += e0.x*w0.x + e0.y*w0.y + e0.z*w0.z + e0.w*w0.w;
      a01 += e1.x*w0.x + e1.y*w0.y + e1.z*w0.z + e1.w*w0.w;
      a10 += e0.x*w1.x + e0.y*w1.y + e0.z*w1.z + e0.w*w1.w;
      a11 += e1.x*w1.x + e1.y*w1.y + e1.z*w1.z + e1.w*w1.w;
    }
    float p;
    p = a00 + bsh[lane];    float v0  = leaky(p)*scsh[lane];
    p = a01 + bsh[lane];    float v0b = leaky(p)*scsh[lane];
    p = a10 + bsh[lane+64]; float v1  = leaky(p)*scsh[lane+64];
    p = a11 + bsh[lane+64]; float v1b = leaky(p)*scsh[lane+64];
    #pragma unroll
    for(int o=1;o<16;o<<=1){
      v0 += __shfl_xor(v0,o); v0b += __shfl_xor(v0b,o);
      v1 += __shfl_xor(v1,o); v1b += __shfl_xor(v1b,o);
    }
    if((lane & 15) == 0){
      int h = lane >> 4;
      float m0 = mask[(size_t)i*NN + j0];
      logitc[((size_t)i*H + h)*NN + s0]     = leaky(v0) + leaky(ss0 + st[j0*H + h]) + m0;
      logitc[((size_t)i*H + h + 4)*NN + s0] = leaky(v1) + leaky(ss1 + st[j0*H + h + 4]) + m0;
      if(s1 < n){
        float m1 = mask[(size_t)i*NN + j1];
        logitc[((size_t)i*H + h)*NN + s1]     = leaky(v0b) + leaky(ss0 + st[j1*H + h]) + m1;
        logitc[((size_t)i*H + h + 4)*NN + s1] = leaky(v1b) + leaky(ss1 + st[j1*H + h + 4]) + m1;
      }
    }
  }
}

// ---------------- K2': compact softmax ----------------
__global__ void k_softmax_c(float* __restrict__ logitc, const int* __restrict__ cnt){
  int i = blockIdx.x;
  int g = threadIdx.x >> 5, l = threadIdx.x & 31;
  int n = cnt[i];
  float* row = logitc + ((size_t)i*H + g)*NN;
  float m = -1e30f;
  for(int s=l; s<n; s+=32) m = fmaxf(m, row[s]);
  #pragma unroll
  for(int o=1;o<32;o<<=1) m = fmaxf(m, __shfl_xor(m, o, 32));
  float sum = 0.f;
  for(int s=l; s<n; s+=32){ float e = expf(row[s]-m); row[s]=e; sum+=e; }
  #pragma unroll
  for(int o=1;o<32;o<<=1) sum += __shfl_xor(sum, o, 32);
  float inv = 1.f/sum;
  for(int s=l; s<n; s+=32) row[s] *= inv;
}

// ---------------- K3': sparse einsum ----------------
__global__ void k_einsum_c(const float* __restrict__ attnc, const int* __restrict__ lists,
                           const int* __restrict__ cnt, const float* __restrict__ npj,
                           float* __restrict__ opre){
  int i = blockIdx.x, c = threadIdx.x;
  int h = c >> 4;
  int n = cnt[i];
  const int* lrow = lists + (size_t)i*NN;
  const float* arow = attnc + ((size_t)i*H + h)*NN;
  float acc = opre[i*HF + c];
  #pragma unroll 4
  for(int s=0; s<n; s++) acc += arow[s] * npj[lrow[s]*HF + c];
  opre[i*HF+c] = acc;
}

// ---------------- K4: node BN stats ----------------
__global__ void k_bn_node_stats(const float* __restrict__ outn_pre, float* __restrict__ stats){
  int c = threadIdx.x & 127, half = threadIdx.x >> 7;
  int r0 = blockIdx.x*16 + half*8;
  float s1=0.f, s2=0.f;
  #pragma unroll
  for(int r=0;r<8;r++){ float v = outn_pre[(r0+r)*HF + c]; s1+=v; s2+=v*v; }
  __shared__ float l1[256], l2[256];
  l1[threadIdx.x]=s1; l2[threadIdx.x]=s2;
  __syncthreads();
  if(threadIdx.x < 128){
    s1 = l1[threadIdx.x] + l1[threadIdx.x+128];
    s2 = l2[threadIdx.x] + l2[threadIdx.x+128];
    atomicAdd(&stats[c], s1); atomicAdd(&stats[HF + c], s2);
  }
}

// ---------------- K5: node BN apply ----------------
__global__ void k_bn_node_apply(const float* __restrict__ outn_pre, const float* __restrict__ stats,
                                const float* __restrict__ g, const float* __restrict__ b,
                                const float* __restrict__ nbias, float* __restrict__ outn){
  int idx = blockIdx.x*256 + threadIdx.x;
  int c = idx & 127;
  float m  = stats[c] * (1.f/NN);
  float var = stats[HF+c]*(1.f/NN) - m*m;
  float xv = outn_pre[idx];
  float y = g[c]*(xv - m)/sqrtf(var + EPS) + b[c] + nbias[c];
  outn[idx] = elu1(y);
}

// ---------------- K6a: m = leaky(sef@Wf1^T+bf1), oes = sef@Wes^T ----------------
__global__ __launch_bounds__(256,3) void k_mlp_a(
    const float* __restrict__ sef, const float* __restrict__ Wf1, const float* __restrict__ bf1,
    const float* __restrict__ Wes, float* __restrict__ m_out, float* __restrict__ oes_out){
  __shared__ float4 Bsh[128*16];   // 32KB
  __shared__ float4 Ash[32*16];    // 8KB
  __shared__ float b1sh[64];
  int tid = threadIdx.x;
  int e0 = blockIdx.x * 32;
  const float4* W1_4 = (const float4*)Wf1;
  const float4* We_4 = (const float4*)Wes;
  #pragma unroll
  for(int t=0;t<8;t++){
    int fi = tid + t*256;            // 0..2047
    int n = fi >> 4, s = fi & 15;
    float4 v = (n < 64) ? W1_4[n*16+s] : We_4[(n-64)*16+s];
    Bsh[n*16 + (s ^ ((n>>3)&15))] = v;
  }
  if(tid < 64) b1sh[tid] = bf1[tid];
  const float4* A4 = (const float4*)(sef + (size_t)e0*EIN);
  #pragma unroll
  for(int t=0;t<2;t++){
    int fi = tid + t*256;            // 0..511
    int e = fi >> 4, s = fi & 15;
    Ash[e*16 + (s ^ ((e>>1)&15))] = A4[fi];
  }
  __syncthreads();
  int og = tid & 15, eg = tid >> 4;  // 8 outputs, 2 edges
  int n0 = og*8, eb = eg*2;
  float acc[2][8] = {};
  #pragma unroll
  for(int s=0;s<16;s++){
    float4 a0 = Ash[(eb+0)*16 + (s ^ (((eb+0)>>1)&15))];
    float4 a1 = Ash[(eb+1)*16 + (s ^ (((eb+1)>>1)&15))];
    #pragma unroll
    for(int oo=0;oo<8;oo++){
      float4 b = Bsh[(n0+oo)*16 + (s ^ (((n0+oo)>>3)&15))];
      acc[0][oo] += a0.x*b.x + a0.y*b.y + a0.z*b.z + a0.w*b.w;
      acc[1][oo] += a1.x*b.x + a1.y*b.y + a1.z*b.z + a1.w*b.w;
    }
  }
  #pragma unroll
  for(int ee=0;ee<2;ee++){
    int e = e0 + eb + ee;
    if(og < 8){
      #pragma unroll
      for(int oo=0;oo<8;oo++) m_out[(size_t)e*EOUT + n0 + oo] = leaky(acc[ee][oo] + b1sh[n0+oo]);
    } else {
      #pragma unroll
      for(int oo=0;oo<8;oo++) oes_out[(size_t)e*EOUT + (n0-64) + oo] = acc[ee][oo];
    }
  }
}

// ---------------- K6b: r = leaky(dd@Wf2^T), dd = (outn[si]-outn[sj])^2 ----------------
__global__ __launch_bounds__(256,3) void k_mlp_b(
    const int* __restrict__ eidx, const float* __restrict__ outn,
    const float* __restrict__ Wf2, float* __restrict__ r_out){
  __shared__ float4 Bsh[64*32];    // 32KB
  __shared__ float4 Ash[32*32];    // 16KB
  int tid = threadIdx.x;
  int e0 = blockIdx.x * 32;
  const float4* W2_4 = (const float4*)Wf2;
  #pragma unroll
  for(int t=0;t<8;t++){
    int fi = tid + t*256;            // 0..2047
    int n = fi >> 5, s = fi & 31;
    Bsh[n*32 + (s ^ ((n>>2)&15))] = W2_4[fi];
  }
  const float4* O4 = (const float4*)outn;
  #pragma unroll
  for(int t=0;t<4;t++){
    int fi = tid + t*256;            // 0..1023
    int e = fi >> 5, s = fi & 31;
    int ed = e0 + e;
    int si = eidx[ed*2], sj = eidx[ed*2+1];
    float4 vi = O4[(size_t)si*32 + s];
    float4 vj = O4[(size_t)sj*32 + s];
    float4 d; d.x=vi.x-vj.x; d.y=vi.y-vj.y; d.z=vi.z-vj.z; d.w=vi.w-vj.w;
    d.x*=d.x; d.y*=d.y; d.z*=d.z; d.w*=d.w;
    Ash[e*32 + (s ^ ((e>>1)&15))] = d;
  }
  __syncthreads();
  int og = tid & 15, eg = tid >> 4;  // 4 outputs, 2 edges
  int o0 = og*4, eb = eg*2;
  float acc[2][4] = {};
  #pragma unroll
  for(int s=0;s<32;s++){
    float4 a0 = Ash[(eb+0)*32 + (s ^ (((eb+0)>>1)&15))];
    float4 a1 = Ash[(eb+1)*32 + (s ^ (((eb+1)>>1)&15))];
    #pragma unroll
    for(int oo=0;oo<4;oo++){
      float4 b = Bsh[(o0+oo)*32 + (s ^ (((o0+oo)>>2)&15))];
      acc[0][oo] += a0.x*b.x + a0.y*b.y + a0.z*b.z + a0.w*b.w;
      acc[1][oo] += a1.x*b.x + a1.y*b.y + a1.z*b.z + a1.w*b.w;
    }
  }
  #pragma unroll
  for(int ee=0;ee<2;ee++){
    float4 v; v.x=leaky(acc[ee][0]); v.y=leaky(acc[ee][1]); v.z=leaky(acc[ee][2]); v.w=leaky(acc[ee][3]);
    *(float4*)(r_out + (size_t)(e0+eb+ee)*EOUT + o0) = v;
  }
}

// ---------------- K6c: oe = [m|r]@Wf3^T + oes ----------------
__global__ __launch_bounds__(256,2) void k_mlp_c(
    const float* __restrict__ m_in, const float* __restrict__ r_in,
    const float* __restrict__ oes_in, const float* __restrict__ Wf3,
    float* __restrict__ oe_pre){
  __shared__ float4 Bsh[64*32];    // 32KB
  __shared__ float4 Ash[32*32];    // 32KB (slots 0-15 = m, 16-31 = r)
  int tid = threadIdx.x;
  int e0 = blockIdx.x * 32;
  const float4* W3_4 = (const float4*)Wf3;
  #pragma unroll
  for(int t=0;t<8;t++){
    int fi = tid + t*256;
    int n = fi >> 5, s = fi & 31;
    Bsh[n*32 + (s ^ ((n>>2)&15))] = W3_4[fi];
  }
  const float4* M4 = (const float4*)(m_in + (size_t)e0*EOUT);
  const float4* R4 = (const float4*)(r_in + (size_t)e0*EOUT);
  #pragma unroll
  for(int t=0;t<2;t++){
    int fi = tid + t*256;            // 0..511
    int e = fi >> 4, s = fi & 15;
    int sw = s ^ ((e>>1)&15);
    Ash[e*32 + sw] = M4[fi];
    Ash[e*32 + 16 + sw] = R4[fi];
  }
  __syncthreads();
  int og = tid & 15, eg = tid >> 4;
  int o0 = og*4, eb = eg*2;
  float acc[2][4] = {};
  #pragma unroll
  for(int s=0;s<32;s++){
    int half = s & 16, sl = s & 15;
    float4 a0 = Ash[(eb+0)*32 + half + (sl ^ (((eb+0)>>1)&15))];
    float4 a1 = Ash[(eb+1)*32 + half + (sl ^ (((eb+1)>>1)&15))];
    #pragma unroll
    for(int oo=0;oo<4;oo++){
      float4 b = Bsh[(o0+oo)*32 + (s ^ (((o0+oo)>>2)&15))];
      acc[0][oo] += a0.x*b.x + a0.y*b.y + a0.z*b.z + a0.w*b.w;
      acc[1][oo] += a1.x*b.x + a1.y*b.y + a1.z*b.z + a1.w*b.w;
    }
  }
  #pragma unroll
  for(int ee=0;ee<2;ee++){
    int e = e0 + eb + ee;
    float4 os = ((const float4*)oes_in)[(size_t)e*16 + og];
    float4 v; v.x=acc[ee][0]+os.x; v.y=acc[ee][1]+os.y; v.z=acc[ee][2]+os.z; v.w=acc[ee][3]+os.w;
    *(float4*)(oe_pre + (size_t)e*EOUT + o0) = v;
  }
}

// ---------------- K6d: edge BN stats ----------------
__global__ void k_bn_edge_stats(const float* __restrict__ oe_pre, float* __restrict__ stats){
  int c = threadIdx.x & 63, rg = threadIdx.x >> 6;
  int r0 = blockIdx.x*256 + rg*64;
  float s1=0.f, s2=0.f;
  for(int r=0;r<64;r++){ float v = oe_pre[(size_t)(r0+r)*EOUT + c]; s1+=v; s2+=v*v; }
  __shared__ float l1[256], l2[256];
  l1[threadIdx.x]=s1; l2[threadIdx.x]=s2;
  __syncthreads();
  if(threadIdx.x < 64){
    float a1 = l1[threadIdx.x] + l1[threadIdx.x+64] + l1[threadIdx.x+128] + l1[threadIdx.x+192];
    float a2 = l2[threadIdx.x] + l2[threadIdx.x+64] + l2[threadIdx.x+128] + l2[threadIdx.x+192];
    atomicAdd(&stats[256 + threadIdx.x], a1);
    atomicAdd(&stats[320 + threadIdx.x], a2);
  }
}

// ---------------- K7: edge BN apply ----------------
__global__ void k_bn_edge_apply(const float* __restrict__ oe_pre, const float* __restrict__ stats,
                                const float* __restrict__ g, const float* __restrict__ b,
                                float* __restrict__ oe_out){
  int idx = blockIdx.x*256 + threadIdx.x;
  int o = idx & 63;
  float m = stats[256+o] * (1.f/E_EDGES);
  float var = stats[320+o]*(1.f/E_EDGES) - m*m;
  float xv = oe_pre[idx];
  float y = g[o]*(xv-m)/sqrtf(var+EPS) + b[o];
  oe_out[idx] = elu1(y);
}

// ---------------- K8: ie nonzero fill ----------------
__global__ __launch_bounds__(256) void k_ie_fill(
    const float* __restrict__ edges, const float* __restrict__ mask,
    const float* __restrict__ Wf4, const float* __restrict__ bf4,
    float* __restrict__ ie){
  __shared__ float w4[64*65];
  __shared__ float b4sh[64];
  __shared__ int list[NN];
  __shared__ int lcnt;
  int i = blockIdx.x, tid = threadIdx.x;
  if(tid==0) lcnt = 0;
  for(int idx=tid; idx<64*64; idx+=256){ int o=idx>>6,k=idx&63; w4[o*65+k]=Wf4[idx]; }
  if(tid<64) b4sh[tid]=bf4[tid];
  __syncthreads();
  for(int t=0;t<3;t++){
    int j = tid + t*256;
    if(mask[i*NN+j] == 0.0f){ int p = atomicAdd(&lcnt,1); list[p]=j; }
  }
  __syncthreads();
  int cnt = lcnt;
  float inv;
  if(cnt == 0){
    for(int t=0;t<3;t++) list[tid+t*256] = tid+t*256;
    cnt = NN; inv = 1.0f/NN;
    __syncthreads();
  } else inv = 1.0f/cnt;
  int o = tid & 63, jj4 = tid >> 6;
  for(int base=0; base<cnt; base+=4){
    int li = base + jj4;
    if(li < cnt){
      int j = list[li];
      const float* er = edges + ((size_t)i*NN + j)*EIN;
      float acc = b4sh[o];
      #pragma unroll 8
      for(int k=0;k<64;k++) acc += er[k]*w4[o*65+k];
      ie[((size_t)i*NN + j)*EIN + o] = acc * inv;
    }
  }
}

// ---------------- K9: scatter ----------------
__global__ void k_winner(const int* __restrict__ eidx, int* __restrict__ winner){
  int e = blockIdx.x*256 + threadIdx.x;
  if(e < E_EDGES){
    int si = eidx[e*2], sj = eidx[e*2+1];
    atomicMax(&winner[si*NN+sj], e);
  }
}
__global__ void k_scatter(const int* __restrict__ eidx, const int* __restrict__ winner,
                          const float* __restrict__ oe, float* __restrict__ ie){
  int idx = blockIdx.x*256 + threadIdx.x;
  int e = idx >> 6, o = idx & 63;
  int si = eidx[e*2], sj = eidx[e*2+1];
  if(winner[si*NN+sj] == e) ie[((size_t)si*NN+sj)*EIN + o] = oe[(size_t)e*64+o];
}

// ---------------- K10: indices -> float ----------------
__global__ void k_idxf(const int* __restrict__ eidx, float* __restrict__ outf){
  int idx = blockIdx.x*256 + threadIdx.x;
  if(idx < E_EDGES*2) outf[idx] = (float)eidx[idx];
}

extern "C" void kernel_launch(void* const* d_in, const int* in_sizes, int n_in,
                              void* d_out, int out_size, void* d_ws, size_t ws_size,
                              hipStream_t stream){
  (void)in_sizes; (void)n_in; (void)out_size; (void)d_ws; (void)ws_size;
  const float* x     = (const float*)d_in[0];
  const float* edges = (const float*)d_in[1];
  const float* mask  = (const float*)d_in[2];
  const float* sef   = (const float*)d_in[3];
  const int*   eidx  = (const int*)d_in[4];
  const float* Wp    = (const float*)d_in[5];
  const float* Wp2   = (const float*)d_in[6];
  const float* bp2   = (const float*)d_in[7];
  const float* ssrc  = (const float*)d_in[8];
  const float* stgt  = (const float*)d_in[9];
  const float* sce   = (const float*)d_in[10];
  const float* Wskip = (const float*)d_in[11];
  const float* nbias = (const float*)d_in[12];
  const float* bng   = (const float*)d_in[13];
  const float* bnb   = (const float*)d_in[14];
  const float* Wf1   = (const float*)d_in[15];
  const float* bf1   = (const float*)d_in[16];
  const float* Wf2   = (const float*)d_in[17];
  const float* Wf3   = (const float*)d_in[18];
  const float* Wf4   = (const float*)d_in[19];
  const float* bf4   = (const float*)d_in[20];
  const float* Wes   = (const float*)d_in[21];
  const float* beg   = (const float*)d_in[22];
  const float* beb   = (const float*)d_in[23];

  float* out      = (float*)d_out;
  float* out_outn = out;                    // 98304
  float* out_ie   = out + 98304;            // 37748736
  float* out_mask = out + 37847040;         // 589824
  float* out_oe   = out + 38436864;         // 1572864
  float* out_idx  = out + 40009728;         // 49152

  // scratch carved out of the (not yet written) ie region
  float* s_logitc = out_ie;                 // 4718592
  float* s_npj    = out_ie + 4718592;       // 98304
  float* s_ss     = s_npj + 98304;          // 6144
  float* s_st     = s_ss + 6144;            // 6144
  float* s_opre   = s_st + 6144;            // 98304
  float* s_oepre  = s_opre + 98304;         // 1572864
  float* s_stats  = s_oepre + 1572864;      // 512
  int*   s_lists  = (int*)(s_stats + 512);  // 2359296
  int*   s_cnt    = s_lists + 2359296;      // 768
  float* s_m      = (float*)(s_cnt + 768);  // 1572864
  float* s_oes    = s_m + 1572864;          // 1572864
  float* s_r      = s_oes + 1572864;        // 1572864
  int*   winner   = (int*)out_mask;         // scratch until mask copied at end

  hipMemsetAsync(s_stats, 0, 512*sizeof(float), stream);
  hipMemsetAsync(winner, 0xFF, (size_t)NN*NN*sizeof(int), stream);

  // k_mlp_a depends only on sef + weights: launch FIRST (diagnostic reorder —
  // round 6 attributed ~1 GB of harness restore/poison traffic to it at its
  // old mid-stream position; if positional, the pollution moves or vanishes).
  k_mlp_a<<<E_EDGES/32, 256, 0, stream>>>(sef, Wf1, bf1, Wes, s_m, s_oes);
  k_list<<<NN/4, 256, 0, stream>>>(mask, s_lists, s_cnt);
  k_proj2<<<96, 256, 0, stream>>>(x, Wp, Wskip, s_npj, s_opre);
  k_scores<<<NN, 128, 0, stream>>>(s_npj, ssrc, stgt, s_ss, s_st);
  k_logits_sparse<<<NN, 256, 0, stream>>>(edges, Wp2, bp2, sce, s_ss, s_st, mask, s_lists, s_cnt, s_logitc);
  k_softmax_c<<<NN, 256, 0, stream>>>(s_logitc, s_cnt);
  k_einsum_c<<<NN, 128, 0, stream>>>(s_logitc, s_lists, s_cnt, s_npj, s_opre);
  k_bn_node_stats<<<48, 256, 0, stream>>>(s_opre, s_stats);
  k_bn_node_apply<<<384, 256, 0, stream>>>(s_opre, s_stats, bng, bnb, nbias, out_outn);
  k_mlp_b<<<E_EDGES/32, 256, 0, stream>>>(eidx, out_outn, Wf2, s_r);
  k_mlp_c<<<E_EDGES/32, 256, 0, stream>>>(s_m, s_r, s_oes, Wf3, s_oepre);
  k_bn_edge_stats<<<E_EDGES/256, 256, 0, stream>>>(s_oepre, s_stats);
  k_bn_edge_apply<<<6144, 256, 0, stream>>>(s_oepre, s_stats, beg, beb, out_oe);
  // all ie-region scratch consumed; now build ie
  hipMemsetAsync(out_ie, 0, (size_t)NN*NN*EIN*sizeof(float), stream);
  k_ie_fill<<<NN, 256, 0, stream>>>(edges, mask, Wf4, bf4, out_ie);
  k_winner<<<96, 256, 0, stream>>>(eidx, winner);
  k_scatter<<<6144, 256, 0, stream>>>(eidx, winner, out_oe, out_ie);
  hipMemcpyAsync(out_mask, mask, (size_t)NN*NN*sizeof(float), hipMemcpyDeviceToDevice, stream);
  k_idxf<<<192, 256, 0, stream>>>(eidx, out_idx);
}